// Round 1
// baseline (28.437 us; speedup 1.0000x reference)
//
#include <hip/hip_runtime.h>

// WICC dynamic-connectivity step, fused edge-update + scatter-add.
// B=16, D=1024, E=D*D. All f32.
// Outputs concatenated: phi_out [B*D] then edge_state_next [B*E].

#define WICC_B 16
#define WICC_D 1024

__global__ __launch_bounds__(256) void wicc_step_kernel(
    const float* __restrict__ state,     // [B, D]
    const float* __restrict__ phi,       // [B, D]
    const float* __restrict__ J,         // [D, D] (dst, src)
    const float* __restrict__ es_in,     // [B, E]
    float* __restrict__ phi_out,         // [B, D]
    float* __restrict__ es_out)          // [B, E]
{
    // XCD-aware remap: block i -> XCD (i&7) under round-robin dispatch.
    // Give each XCD a contiguous 128-dst slab across all 16 batches so its
    // J working set (128 rows * 4KB = 512KB) stays L2-resident.
    const int i    = blockIdx.x;          // 0 .. B*D-1 (16384)
    const int xcd  = i & 7;
    const int slot = i >> 3;              // 0 .. 2047
    const int b    = slot & 15;           // iterate batch fastest -> 16
    const int dst  = xcd * 128 + (slot >> 4);   // consecutive slots share J row

    const int t = threadIdx.x;            // 0..255, each owns 4 src

    const float* __restrict__ srow = state + (size_t)b * WICC_D;
    const float* __restrict__ jrow = J + (size_t)dst * WICC_D;
    const size_t ebase = (size_t)b * (size_t)(WICC_D) * (size_t)(WICC_D)
                       + (size_t)dst * (size_t)WICC_D;

    const float4 s4 = reinterpret_cast<const float4*>(srow)[t];
    const float4 j4 = reinterpret_cast<const float4*>(jrow)[t];
    const float4 e4 = reinterpret_cast<const float4*>(es_in + ebase)[t];

    const float J_IN = 0.38f, GP = 1e-3f, GM = 1e-3f, BIAS = 2.0f, TH = 0.1675f;

    float4 o4;
    float acc = 0.0f;
    const float* sp = &s4.x;
    const float* jp = &j4.x;
    const float* ep = &e4.x;
    float* op = &o4.x;
    #pragma unroll
    for (int k = 0; k < 4; ++k) {
        const float x  = sp[k] * J_IN;
        const float jj = jp[k];
        const float es = ep[k];
        const float pa = x + jj;
        const float pb = x - jj;
        const float ca = BIAS - es;
        const float cb = BIAS + es;
        const float ra = sqrtf(fmaxf(ca * ca - 1.0f, 0.0f));
        const float rb = sqrtf(fmaxf(cb * cb - 1.0f, 0.0f));
        const float ga = (fabsf(pa) > TH) ? ra : 0.0f;
        const float gb = (fabsf(pb) > TH) ? rb : 0.0f;
        const float esn = es + (GP * (ga - gb) - GM * es);   // DT = 1
        op[k] = esn;
        acc += esn;
    }

    reinterpret_cast<float4*>(es_out + ebase)[t] = o4;

    // Row-sum reduction: wave64 shuffle, then 4 partials via LDS.
    #pragma unroll
    for (int off = 32; off > 0; off >>= 1)
        acc += __shfl_down(acc, off, 64);

    __shared__ float lds[4];
    if ((t & 63) == 0) lds[t >> 6] = acc;
    __syncthreads();
    if (t == 0) {
        const float tot = lds[0] + lds[1] + lds[2] + lds[3];
        const int node = b * WICC_D + dst;
        phi_out[node] = phi[node] + 0.38f * tot;   // J_OUT = 0.38
    }
}

extern "C" void kernel_launch(void* const* d_in, const int* in_sizes, int n_in,
                              void* d_out, int out_size, void* d_ws, size_t ws_size,
                              hipStream_t stream) {
    const float* state = (const float*)d_in[0];   // [B, D]
    const float* phi   = (const float*)d_in[1];   // [B, D]
    const float* J     = (const float*)d_in[2];   // [D, D]
    const float* es    = (const float*)d_in[3];   // [B, E]

    float* phi_out = (float*)d_out;                         // [B*D]
    float* es_out  = (float*)d_out + WICC_B * WICC_D;       // [B*E]

    wicc_step_kernel<<<dim3(WICC_B * WICC_D), dim3(256), 0, stream>>>(
        state, phi, J, es, phi_out, es_out);
}